// Round 1
// baseline (60.904 us; speedup 1.0000x reference)
//
#include <hip/hip_runtime.h>
#include <math.h>

#define NQ     12
#define DIM    4096
#define DEPTH  4
#define TPB    256

// One block per batch sample. State (re,im) lives in LDS.
// Circuit: RX layer folded into closed-form init; 4 x (12 RY passes + fused CZ
// sign pass); then probs -> z_i = T - 2*S_i reduction; head + log_softmax.
__global__ __launch_bounds__(TPB) void qsim_kernel(
    const float* __restrict__ x,        // (512, 12) RX angles
    const float* __restrict__ params,   // (48, 12)  RY angles (shared across batch)
    const float* __restrict__ head_w,   // (2, 12)
    const float* __restrict__ head_b,   // (2,)
    float* __restrict__ out)            // (512, 2) log-softmax
{
    __shared__ float re[DIM];
    __shared__ float im[DIM];
    __shared__ float cys[DEPTH * NQ];
    __shared__ float sys[DEPTH * NQ];
    __shared__ float red[4 * 13];       // 4 waves x (T, S_0..S_11)

    const int b   = blockIdx.x;
    const int tid = threadIdx.x;

    // RY angle table (batch-independent): th = 0.5 * params[d*NQ+i, i]
    if (tid < DEPTH * NQ) {
        int i = tid % NQ;
        float th = 0.5f * params[tid * NQ + i];
        cys[tid] = cosf(th);
        sys[tid] = sinf(th);
    }

    // Per-sample RX coefficients (redundant per thread; 12 sincos, cheap).
    float c[NQ], s[NQ];
    #pragma unroll
    for (int i = 0; i < NQ; ++i) {
        float half = 0.5f * x[b * NQ + i];
        c[i] = cosf(half);
        s[i] = sinf(half);
    }

    // Closed-form initial state after the RX layer:
    // amp[k] = (-i)^popc(k) * prod_i (bit_{11-i}(k) ? s_i : c_i)
    for (int k = tid; k < DIM; k += TPB) {
        float r = 1.0f;
        #pragma unroll
        for (int i = 0; i < NQ; ++i)
            r *= ((k >> (NQ - 1 - i)) & 1) ? s[i] : c[i];
        int w = __popc(k) & 3;
        re[k] = (w == 0) ? r : ((w == 2) ? -r : 0.0f);
        im[k] = (w == 1) ? -r : ((w == 3) ? r : 0.0f);
    }

    for (int d = 0; d < DEPTH; ++d) {
        for (int i = 0; i < NQ; ++i) {
            __syncthreads();
            const float cy = cys[d * NQ + i];
            const float sy = sys[d * NQ + i];
            const int stride = 1 << (NQ - 1 - i);
            // 2048 butterfly pairs, 8 per thread
            for (int p = tid; p < DIM / 2; p += TPB) {
                int i0 = ((p & ~(stride - 1)) << 1) | (p & (stride - 1));
                int i1 = i0 + stride;
                float r0 = re[i0], r1 = re[i1];
                float m0 = im[i0], m1 = im[i1];
                re[i0] = cy * r0 - sy * r1;
                re[i1] = sy * r0 + cy * r1;
                im[i0] = cy * m0 - sy * m1;
                im[i1] = sy * m0 + cy * m1;
            }
        }
        __syncthreads();
        // Fused CZ chain: negate where the 12-bit index has an odd number of
        // adjacent set-bit pairs.
        for (int k = tid; k < DIM; k += TPB) {
            if (__popc(k & (k >> 1)) & 1) {
                re[k] = -re[k];
                im[k] = -im[k];
            }
        }
    }
    __syncthreads();

    // probs -> (T, S_i) streaming reduction
    float tacc = 0.0f;
    float sacc[NQ];
    #pragma unroll
    for (int i = 0; i < NQ; ++i) sacc[i] = 0.0f;
    for (int k = tid; k < DIM; k += TPB) {
        float p = re[k] * re[k] + im[k] * im[k];
        tacc += p;
        #pragma unroll
        for (int i = 0; i < NQ; ++i)
            if ((k >> (NQ - 1 - i)) & 1) sacc[i] += p;
    }
    // wave (64-lane) shuffle reduction
    #pragma unroll
    for (int off = 32; off > 0; off >>= 1) {
        tacc += __shfl_down(tacc, off);
        #pragma unroll
        for (int i = 0; i < NQ; ++i) sacc[i] += __shfl_down(sacc[i], off);
    }
    const int wave = tid >> 6;
    if ((tid & 63) == 0) {
        red[wave * 13] = tacc;
        #pragma unroll
        for (int i = 0; i < NQ; ++i) red[wave * 13 + 1 + i] = sacc[i];
    }
    __syncthreads();

    if (tid == 0) {
        float T = red[0] + red[13] + red[26] + red[39];
        float l0 = head_b[0], l1 = head_b[1];
        #pragma unroll
        for (int i = 0; i < NQ; ++i) {
            float S = red[1 + i] + red[14 + i] + red[27 + i] + red[40 + i];
            float z = T - 2.0f * S;
            l0 += z * head_w[i];
            l1 += z * head_w[NQ + i];
        }
        float m = fmaxf(l0, l1);
        float lse = m + logf(expf(l0 - m) + expf(l1 - m));
        out[b * 2 + 0] = l0 - lse;
        out[b * 2 + 1] = l1 - lse;
    }
}

extern "C" void kernel_launch(void* const* d_in, const int* in_sizes, int n_in,
                              void* d_out, int out_size, void* d_ws, size_t ws_size,
                              hipStream_t stream) {
    const float* x      = (const float*)d_in[0];
    const float* params = (const float*)d_in[1];
    const float* head_w = (const float*)d_in[2];
    const float* head_b = (const float*)d_in[3];
    float* out = (float*)d_out;

    const int batch = in_sizes[0] / NQ;   // 512
    qsim_kernel<<<batch, TPB, 0, stream>>>(x, params, head_w, head_b, out);
}

// Round 2
// 26.170 us; speedup vs baseline: 2.3272x; 2.3272x over previous
//
#include <hip/hip_runtime.h>
#include <math.h>

#define NQ    12
#define TPB   256
#define DEPTH 4

// ---- cross-lane helpers ------------------------------------------------
// masks 1,2 -> DPP quad_perm; mask 8 -> DPP row_ror:8 (all VALU pipe).
// masks 4,16,32 -> __shfl_xor (ds_swizzle / bpermute, LDS pipe).
template<int CTRL>
__device__ __forceinline__ float dppf(float v) {
    int r = __builtin_amdgcn_update_dpp(0, __float_as_int(v), CTRL, 0xF, 0xF, true);
    return __int_as_float(r);
}

template<int M>
__device__ __forceinline__ float xsh(float v) {
    if constexpr (M == 1)      return dppf<0xB1>(v);    // quad_perm [1,0,3,2] = xor 1
    else if constexpr (M == 2) return dppf<0x4E>(v);    // quad_perm [2,3,0,1] = xor 2
    else if constexpr (M == 8) return dppf<0x128>(v);   // row_ror:8 = xor 8 (16-lane rows)
    else                       return __shfl_xor(v, M, 64);
}

// RY butterfly across a lane-bit wire. bit = my wire bit.
// bit==0: new = cy*v - sy*p ; bit==1: new = cy*v + sy*p
template<int M>
__device__ __forceinline__ void wave_wire(float re[16], float im[16],
                                          float cy, float sy, int bit) {
    const float ssy = bit ? sy : -sy;
    #pragma unroll
    for (int e = 0; e < 16; ++e) {
        float pr = xsh<M>(re[e]);
        float pi = xsh<M>(im[e]);
        re[e] = fmaf(ssy, pr, cy * re[e]);
        im[e] = fmaf(ssy, pi, cy * im[e]);
    }
}

// RY butterfly on an elem-bit wire (stride ST within the 16 local amps).
template<int ST>
__device__ __forceinline__ void reg_wire(float re[16], float im[16],
                                         float cy, float sy) {
    #pragma unroll
    for (int e0 = 0; e0 < 16; ++e0) {
        if ((e0 & ST) == 0) {
            const int e1 = e0 | ST;
            float r0 = re[e0], r1 = re[e1];
            re[e0] = fmaf(cy, r0, -sy * r1);
            re[e1] = fmaf(sy, r0,  cy * r1);
            float i0 = im[e0], i1 = im[e1];
            im[e0] = fmaf(cy, i0, -sy * i1);
            im[e1] = fmaf(sy, i0,  cy * i1);
        }
    }
}

__global__ __launch_bounds__(TPB) void qsim_kernel(
    const float* __restrict__ x,        // (512, 12)
    const float* __restrict__ params,   // (48, 12)
    const float* __restrict__ head_w,   // (2, 12)
    const float* __restrict__ head_b,   // (2,)
    float* __restrict__ out)            // (512, 2)
{
    __shared__ float4 exch[8][TPB];     // 32 KB 4-way exchange buffer
    __shared__ float  cys[DEPTH * NQ];
    __shared__ float  sys[DEPTH * NQ];
    __shared__ float  red[4][13];

    const int b = blockIdx.x;
    const int t = threadIdx.x;

    // gate angle tables (batch-independent)
    if (t < DEPTH * NQ) {
        int i = t % NQ;
        float th = 0.5f * params[t * NQ + i];
        cys[t] = cosf(th);
        sys[t] = sinf(th);
    }

    // per-sample RX coefficients
    float c[NQ], s[NQ];
    #pragma unroll
    for (int i = 0; i < NQ; ++i) {
        float h = 0.5f * x[b * NQ + i];
        c[i] = cosf(h);
        s[i] = sinf(h);
    }

    // state: amp index k = (t<<4)|e ; re/im in registers
    float re[16], im[16];
    {
        float P = 1.0f;
        #pragma unroll
        for (int j = 0; j < 8; ++j)
            P *= ((t >> (7 - j)) & 1) ? s[j] : c[j];
        const int pt = __popc(t);
        #pragma unroll
        for (int e = 0; e < 16; ++e) {
            float q = ((e >> 3) & 1 ? s[8]  : c[8])
                    * ((e >> 2) & 1 ? s[9]  : c[9])
                    * ((e >> 1) & 1 ? s[10] : c[10])
                    * ((e     ) & 1 ? s[11] : c[11]);
            float m = P * q;
            int p = (pt + __popc(e)) & 3;   // (-i)^popc(k)
            re[e] = (p == 0) ? m : ((p == 2) ? -m : 0.0f);
            im[e] = (p == 1) ? -m : ((p == 3) ? m : 0.0f);
        }
    }

    // CZ sign mask: negate where popc(k & (k>>1)) is odd
    unsigned czm = 0;
    #pragma unroll
    for (int e = 0; e < 16; ++e) {
        int k = (t << 4) | e;
        if (__popc(k & (k >> 1)) & 1) czm |= (1u << e);
    }

    const int a = (t >> 7) & 1;   // wire-0 bit (k bit 11)
    const int bb = (t >> 6) & 1;  // wire-1 bit (k bit 10)
    const int tb = t ^ 64, ta = t ^ 128, tab = t ^ 192;

    __syncthreads();   // cys/sys ready

    for (int d = 0; d < DEPTH; ++d) {
        const int base = d * NQ;

        // elem-bit wires 8..11 (strides 8,4,2,1)
        reg_wire<8>(re, im, cys[base + 8],  sys[base + 8]);
        reg_wire<4>(re, im, cys[base + 9],  sys[base + 9]);
        reg_wire<2>(re, im, cys[base + 10], sys[base + 10]);
        reg_wire<1>(re, im, cys[base + 11], sys[base + 11]);

        // lane-bit wires 2..7
        wave_wire<32>(re, im, cys[base + 2], sys[base + 2], (t >> 5) & 1);
        wave_wire<16>(re, im, cys[base + 3], sys[base + 3], (t >> 4) & 1);
        wave_wire<8 >(re, im, cys[base + 4], sys[base + 4], (t >> 3) & 1);
        wave_wire<4 >(re, im, cys[base + 5], sys[base + 5], (t >> 2) & 1);
        wave_wire<2 >(re, im, cys[base + 6], sys[base + 6], (t >> 1) & 1);
        wave_wire<1 >(re, im, cys[base + 7], sys[base + 7], (t     ) & 1);

        // wires 0,1 fused: 4-way exchange across thread bits 7,6 via LDS
        {
            const float c0 = cys[base + 0], s0 = sys[base + 0];
            const float c1 = cys[base + 1], s1 = sys[base + 1];
            const float sa = a  ? s0 : -s0;
            const float sb = bb ? s1 : -s1;
            const float k_oo = c0 * c1;
            const float k_b  = c0 * sb;   // coeff of partner with wire-1 bit flipped (t^64)
            const float k_a  = sa * c1;   // wire-0 bit flipped (t^128)
            const float k_ab = sa * sb;   // both flipped (t^192)

            __syncthreads();   // protect previous iteration's reads
            #pragma unroll
            for (int j = 0; j < 4; ++j) {
                exch[j][t]     = make_float4(re[4*j], re[4*j+1], re[4*j+2], re[4*j+3]);
                exch[4 + j][t] = make_float4(im[4*j], im[4*j+1], im[4*j+2], im[4*j+3]);
            }
            __syncthreads();
            #pragma unroll
            for (int j = 0; j < 4; ++j) {
                float4 rb  = exch[j][tb],     ra  = exch[j][ta],     rab  = exch[j][tab];
                float4 ib  = exch[4 + j][tb], ia  = exch[4 + j][ta], iab  = exch[4 + j][tab];
                re[4*j+0] = k_oo * re[4*j+0] + k_b * rb.x + k_a * ra.x + k_ab * rab.x;
                re[4*j+1] = k_oo * re[4*j+1] + k_b * rb.y + k_a * ra.y + k_ab * rab.y;
                re[4*j+2] = k_oo * re[4*j+2] + k_b * rb.z + k_a * ra.z + k_ab * rab.z;
                re[4*j+3] = k_oo * re[4*j+3] + k_b * rb.w + k_a * ra.w + k_ab * rab.w;
                im[4*j+0] = k_oo * im[4*j+0] + k_b * ib.x + k_a * ia.x + k_ab * iab.x;
                im[4*j+1] = k_oo * im[4*j+1] + k_b * ib.y + k_a * ia.y + k_ab * iab.y;
                im[4*j+2] = k_oo * im[4*j+2] + k_b * ib.z + k_a * ia.z + k_ab * iab.z;
                im[4*j+3] = k_oo * im[4*j+3] + k_b * ib.w + k_a * ia.w + k_ab * iab.w;
            }
        }

        // CZ signs (skip last depth: |amp|^2 unaffected)
        if (d < DEPTH - 1) {
            #pragma unroll
            for (int e = 0; e < 16; ++e) {
                int sb2 = (int)(((czm >> e) & 1u) << 31);
                re[e] = __int_as_float(__float_as_int(re[e]) ^ sb2);
                im[e] = __int_as_float(__float_as_int(im[e]) ^ sb2);
            }
        }
    }

    // ---- reduction: T and per-wire S ----
    float T = 0.f, E0 = 0.f, E1 = 0.f, E2 = 0.f, E3 = 0.f;
    #pragma unroll
    for (int e = 0; e < 16; ++e) {
        float p = re[e] * re[e] + im[e] * im[e];
        T += p;
        if (e & 8) E0 += p;   // wire 8
        if (e & 4) E1 += p;   // wire 9
        if (e & 2) E2 += p;   // wire 10
        if (e & 1) E3 += p;   // wire 11
    }
    float v[13];
    v[0] = T;
    #pragma unroll
    for (int w = 0; w < 8; ++w)
        v[1 + w] = ((t >> (7 - w)) & 1) ? T : 0.0f;   // wires 0..7
    v[9]  = E0; v[10] = E1; v[11] = E2; v[12] = E3;

    #pragma unroll
    for (int i = 0; i < 13; ++i) {
        float y = v[i];
        y += xsh<1>(y);  y += xsh<2>(y);  y += xsh<4>(y);
        y += xsh<8>(y);  y += xsh<16>(y); y += xsh<32>(y);
        v[i] = y;
    }
    if ((t & 63) == 0) {
        #pragma unroll
        for (int i = 0; i < 13; ++i) red[t >> 6][i] = v[i];
    }
    __syncthreads();

    if (t == 0) {
        float Tt = red[0][0] + red[1][0] + red[2][0] + red[3][0];
        float l0 = head_b[0], l1 = head_b[1];
        #pragma unroll
        for (int w = 0; w < NQ; ++w) {
            float Sw = red[0][1 + w] + red[1][1 + w] + red[2][1 + w] + red[3][1 + w];
            float z = Tt - 2.0f * Sw;
            l0 += z * head_w[w];
            l1 += z * head_w[NQ + w];
        }
        float m = fmaxf(l0, l1);
        float lse = m + logf(expf(l0 - m) + expf(l1 - m));
        out[b * 2 + 0] = l0 - lse;
        out[b * 2 + 1] = l1 - lse;
    }
}

extern "C" void kernel_launch(void* const* d_in, const int* in_sizes, int n_in,
                              void* d_out, int out_size, void* d_ws, size_t ws_size,
                              hipStream_t stream) {
    const float* x      = (const float*)d_in[0];
    const float* params = (const float*)d_in[1];
    const float* head_w = (const float*)d_in[2];
    const float* head_b = (const float*)d_in[3];
    float* out = (float*)d_out;

    const int batch = in_sizes[0] / NQ;   // 512
    qsim_kernel<<<batch, TPB, 0, stream>>>(x, params, head_w, head_b, out);
}

// Round 4
// 23.763 us; speedup vs baseline: 2.5630x; 1.1013x over previous
//
#include <hip/hip_runtime.h>
#include <math.h>

#define NQ    12
#define TPB   256
#define DEPTH 4

// ---- cross-lane helpers (all VALU pipe) --------------------------------
template<int CTRL>
__device__ __forceinline__ float dppf(float v) {
    int r = __builtin_amdgcn_update_dpp(0, __float_as_int(v), CTRL, 0xF, 0xF, true);
    return __int_as_float(r);
}

#if __has_builtin(__builtin_amdgcn_permlane32_swap)
#define HAVE_PL32 1
#else
#define HAVE_PL32 0
#endif
#if __has_builtin(__builtin_amdgcn_permlane16_swap)
#define HAVE_PL16 1
#else
#define HAVE_PL16 0
#endif

// split value into (low-half bcast, high-half bcast) across lane-bit 5.
// CDNA4 v_permlane32_swap_b32: VDST rows 2-3 <-> VSRC rows 0-1; with both
// operands = v, r[0] = v[lane & ~32], r[1] = v[lane | 32].
__device__ __forceinline__ void split32(float v, float& v0, float& v1) {
#if HAVE_PL32
    auto r = __builtin_amdgcn_permlane32_swap(__float_as_uint(v), __float_as_uint(v), false, false);
    v0 = __uint_as_float(r[0]);
    v1 = __uint_as_float(r[1]);
#else
    float p = __shfl_xor(v, 32, 64);
    int bit = (__lane_id() >> 5) & 1;
    v0 = bit ? p : v;
    v1 = bit ? v : p;
#endif
}
// same across lane-bit 4 (VDST odd 16-rows <-> VSRC even 16-rows)
__device__ __forceinline__ void split16(float v, float& v0, float& v1) {
#if HAVE_PL16
    auto r = __builtin_amdgcn_permlane16_swap(__float_as_uint(v), __float_as_uint(v), false, false);
    v0 = __uint_as_float(r[0]);
    v1 = __uint_as_float(r[1]);
#else
    float p = __shfl_xor(v, 16, 64);
    int bit = (__lane_id() >> 4) & 1;
    v0 = bit ? p : v;
    v1 = bit ? v : p;
#endif
}

// ---- butterfly variants ------------------------------------------------
// single-DPP partner (masks 1,2,8): n = cy*v + ssy*partner
template<int CTRL>
__device__ __forceinline__ void dpp_wire(float re[16], float im[16],
                                         float cy, float sy, int bit) {
    const float ssy = bit ? sy : -sy;
    #pragma unroll
    for (int e = 0; e < 16; ++e) {
        float pr = dppf<CTRL>(re[e]);
        float pi = dppf<CTRL>(im[e]);
        re[e] = fmaf(ssy, pr, cy * re[e]);
        im[e] = fmaf(ssy, pi, cy * im[e]);
    }
}

// mask 4: partner via DPP row shifts.
// row_shr:n sources lane i-n; row_shl:n sources lane i+n (GCN convention,
// cf. the canonical row_shr:1 prefix-sum idiom).
// bit==0 lanes need partner i+4 -> row_shl:4 (0x104);
// bit==1 lanes need partner i-4 -> row_shr:4 (0x114).
__device__ __forceinline__ void xor4_wire(float re[16], float im[16],
                                          float cy, float sy, int bit) {
    const float ssy = bit ? sy : -sy;
    #pragma unroll
    for (int e = 0; e < 16; ++e) {
        float prS = dppf<0x114>(re[e]);   // row_shr:4 -> src lane i-4
        float prL = dppf<0x104>(re[e]);   // row_shl:4 -> src lane i+4
        float piS = dppf<0x114>(im[e]);
        float piL = dppf<0x104>(im[e]);
        float pr = bit ? prS : prL;
        float pi = bit ? piS : piL;
        re[e] = fmaf(ssy, pr, cy * re[e]);
        im[e] = fmaf(ssy, pi, cy * im[e]);
    }
}

// masks 16/32 via permlane swap: n = ka*v0 + kb*v1
template<bool IS32>
__device__ __forceinline__ void pl_wire(float re[16], float im[16],
                                        float cy, float sy, int bit) {
    const float ka = bit ? sy : cy;
    const float kb = bit ? cy : -sy;
    #pragma unroll
    for (int e = 0; e < 16; ++e) {
        float r0, r1, i0, i1;
        if constexpr (IS32) { split32(re[e], r0, r1); split32(im[e], i0, i1); }
        else               { split16(re[e], r0, r1); split16(im[e], i0, i1); }
        re[e] = fmaf(ka, r0, kb * r1);
        im[e] = fmaf(ka, i0, kb * i1);
    }
}

// elem-bit butterfly (stride ST within the 16 local amps)
template<int ST>
__device__ __forceinline__ void reg_wire(float re[16], float im[16],
                                         float cy, float sy) {
    #pragma unroll
    for (int e0 = 0; e0 < 16; ++e0) {
        if ((e0 & ST) == 0) {
            const int e1 = e0 | ST;
            float r0 = re[e0], r1 = re[e1];
            re[e0] = fmaf(cy, r0, -sy * r1);
            re[e1] = fmaf(sy, r0,  cy * r1);
            float i0 = im[e0], i1 = im[e1];
            im[e0] = fmaf(cy, i0, -sy * i1);
            im[e1] = fmaf(sy, i0,  cy * i1);
        }
    }
}

// all-VALU wave sum (quads uniform after first two steps -> ror works;
// split16/split32 sums are order-insensitive)
__device__ __forceinline__ float wave_sum(float y) {
    y += dppf<0xB1>(y);     // xor 1
    y += dppf<0x4E>(y);     // xor 2
    y += dppf<0x124>(y);    // row_ror:4
    y += dppf<0x128>(y);    // row_ror:8
    float a, b;
    split16(y, a, b); y = a + b;
    split32(y, a, b); y = a + b;
    return y;
}

__global__ __launch_bounds__(TPB) void qsim_kernel(
    const float* __restrict__ x,        // (512, 12)
    const float* __restrict__ params,   // (48, 12)
    const float* __restrict__ head_w,   // (2, 12)
    const float* __restrict__ head_b,   // (2,)
    float* __restrict__ out)            // (512, 2)
{
    __shared__ float4 exch[8][TPB];     // 32 KB 4-way exchange buffer
    __shared__ float  cys[DEPTH * NQ];
    __shared__ float  sys[DEPTH * NQ];
    __shared__ float  red[4][13];

    const int b = blockIdx.x;
    const int t = threadIdx.x;

    // gate angle tables (batch-independent)
    if (t < DEPTH * NQ) {
        int i = t % NQ;
        float sv, cv;
        __sincosf(0.5f * params[t * NQ + i], &sv, &cv);
        cys[t] = cv;
        sys[t] = sv;
    }

    // per-sample RX coefficients
    float c[NQ], s[NQ];
    #pragma unroll
    for (int i = 0; i < NQ; ++i)
        __sincosf(0.5f * x[b * NQ + i], &s[i], &c[i]);

    // state: amp index k = (t<<4)|e ; re/im in registers
    float re[16], im[16];
    {
        float P = 1.0f;
        #pragma unroll
        for (int j = 0; j < 8; ++j)
            P *= ((t >> (7 - j)) & 1) ? s[j] : c[j];
        const int pt = __popc(t);
        #pragma unroll
        for (int e = 0; e < 16; ++e) {
            float q = ((e >> 3) & 1 ? s[8]  : c[8])
                    * ((e >> 2) & 1 ? s[9]  : c[9])
                    * ((e >> 1) & 1 ? s[10] : c[10])
                    * ((e     ) & 1 ? s[11] : c[11]);
            float m = P * q;
            int p = (pt + __popc(e)) & 3;   // (-i)^popc(k)
            re[e] = (p == 0) ? m : ((p == 2) ? -m : 0.0f);
            im[e] = (p == 1) ? -m : ((p == 3) ? m : 0.0f);
        }
    }

    // CZ sign mask: negate where popc(k & (k>>1)) odd
    unsigned czm = 0;
    #pragma unroll
    for (int e = 0; e < 16; ++e) {
        int k = (t << 4) | e;
        if (__popc(k & (k >> 1)) & 1) czm |= (1u << e);
    }

    const int a  = (t >> 7) & 1;   // wire-0 bit
    const int bb = (t >> 6) & 1;   // wire-1 bit
    const int tb = t ^ 64, ta = t ^ 128, tab = t ^ 192;

    __syncthreads();   // tables ready

    for (int d = 0; d < DEPTH; ++d) {
        const int base = d * NQ;

        // elem-bit wires 8..11
        reg_wire<8>(re, im, cys[base + 8],  sys[base + 8]);
        reg_wire<4>(re, im, cys[base + 9],  sys[base + 9]);
        reg_wire<2>(re, im, cys[base + 10], sys[base + 10]);
        reg_wire<1>(re, im, cys[base + 11], sys[base + 11]);

        // lane-bit wires 2..7 (all VALU pipe)
        pl_wire<true >(re, im, cys[base + 2], sys[base + 2], (t >> 5) & 1);
        pl_wire<false>(re, im, cys[base + 3], sys[base + 3], (t >> 4) & 1);
        dpp_wire<0x128>(re, im, cys[base + 4], sys[base + 4], (t >> 3) & 1); // xor 8
        xor4_wire      (re, im, cys[base + 5], sys[base + 5], (t >> 2) & 1); // xor 4
        dpp_wire<0x4E >(re, im, cys[base + 6], sys[base + 6], (t >> 1) & 1); // xor 2
        dpp_wire<0xB1 >(re, im, cys[base + 7], sys[base + 7], (t     ) & 1); // xor 1

        // wires 0,1 fused: 4-way exchange across thread bits 7,6 via LDS
        {
            const float c0 = cys[base + 0], s0 = sys[base + 0];
            const float c1 = cys[base + 1], s1 = sys[base + 1];
            const float sa = a  ? s0 : -s0;
            const float sb = bb ? s1 : -s1;
            const float k_oo = c0 * c1;
            const float k_b  = c0 * sb;
            const float k_a  = sa * c1;
            const float k_ab = sa * sb;

            __syncthreads();
            #pragma unroll
            for (int j = 0; j < 4; ++j) {
                exch[j][t]     = make_float4(re[4*j], re[4*j+1], re[4*j+2], re[4*j+3]);
                exch[4 + j][t] = make_float4(im[4*j], im[4*j+1], im[4*j+2], im[4*j+3]);
            }
            __syncthreads();
            #pragma unroll
            for (int j = 0; j < 4; ++j) {
                float4 rb  = exch[j][tb],     ra  = exch[j][ta],     rab  = exch[j][tab];
                float4 ib  = exch[4 + j][tb], ia  = exch[4 + j][ta], iab  = exch[4 + j][tab];
                re[4*j+0] = k_oo * re[4*j+0] + k_b * rb.x + k_a * ra.x + k_ab * rab.x;
                re[4*j+1] = k_oo * re[4*j+1] + k_b * rb.y + k_a * ra.y + k_ab * rab.y;
                re[4*j+2] = k_oo * re[4*j+2] + k_b * rb.z + k_a * ra.z + k_ab * rab.z;
                re[4*j+3] = k_oo * re[4*j+3] + k_b * rb.w + k_a * ra.w + k_ab * rab.w;
                im[4*j+0] = k_oo * im[4*j+0] + k_b * ib.x + k_a * ia.x + k_ab * iab.x;
                im[4*j+1] = k_oo * im[4*j+1] + k_b * ib.y + k_a * ia.y + k_ab * iab.y;
                im[4*j+2] = k_oo * im[4*j+2] + k_b * ib.z + k_a * ia.z + k_ab * iab.z;
                im[4*j+3] = k_oo * im[4*j+3] + k_b * ib.w + k_a * ia.w + k_ab * iab.w;
            }
        }

        // CZ signs (skip last depth: |amp|^2 unaffected)
        if (d < DEPTH - 1) {
            #pragma unroll
            for (int e = 0; e < 16; ++e) {
                int sb2 = (int)(((czm >> e) & 1u) << 31);
                re[e] = __int_as_float(__float_as_int(re[e]) ^ sb2);
                im[e] = __int_as_float(__float_as_int(im[e]) ^ sb2);
            }
        }
    }

    // ---- reduction: T and per-wire S ----
    float T = 0.f, E0 = 0.f, E1 = 0.f, E2 = 0.f, E3 = 0.f;
    #pragma unroll
    for (int e = 0; e < 16; ++e) {
        float p = re[e] * re[e] + im[e] * im[e];
        T += p;
        if (e & 8) E0 += p;
        if (e & 4) E1 += p;
        if (e & 2) E2 += p;
        if (e & 1) E3 += p;
    }
    float v[13];
    v[0] = T;
    #pragma unroll
    for (int w = 0; w < 8; ++w)
        v[1 + w] = ((t >> (7 - w)) & 1) ? T : 0.0f;   // wires 0..7
    v[9] = E0; v[10] = E1; v[11] = E2; v[12] = E3;

    #pragma unroll
    for (int i = 0; i < 13; ++i)
        v[i] = wave_sum(v[i]);

    if ((t & 63) == 0) {
        #pragma unroll
        for (int i = 0; i < 13; ++i) red[t >> 6][i] = v[i];
    }
    __syncthreads();

    if (t == 0) {
        float Tt = red[0][0] + red[1][0] + red[2][0] + red[3][0];
        float l0 = head_b[0], l1 = head_b[1];
        #pragma unroll
        for (int w = 0; w < NQ; ++w) {
            float Sw = red[0][1 + w] + red[1][1 + w] + red[2][1 + w] + red[3][1 + w];
            float z = Tt - 2.0f * Sw;
            l0 += z * head_w[w];
            l1 += z * head_w[NQ + w];
        }
        float m = fmaxf(l0, l1);
        float lse = m + __logf(__expf(l0 - m) + __expf(l1 - m));
        out[b * 2 + 0] = l0 - lse;
        out[b * 2 + 1] = l1 - lse;
    }
}

extern "C" void kernel_launch(void* const* d_in, const int* in_sizes, int n_in,
                              void* d_out, int out_size, void* d_ws, size_t ws_size,
                              hipStream_t stream) {
    const float* x      = (const float*)d_in[0];
    const float* params = (const float*)d_in[1];
    const float* head_w = (const float*)d_in[2];
    const float* head_b = (const float*)d_in[3];
    float* out = (float*)d_out;

    const int batch = in_sizes[0] / NQ;   // 512
    qsim_kernel<<<batch, TPB, 0, stream>>>(x, params, head_w, head_b, out);
}

// Round 5
// 22.020 us; speedup vs baseline: 2.7659x; 1.0792x over previous
//
#include <hip/hip_runtime.h>
#include <math.h>

#define NQ    12
#define TPB   256
#define DEPTH 4

typedef float v2f __attribute__((ext_vector_type(2)));

__device__ __forceinline__ v2f splat(float s) { return (v2f){s, s}; }
__device__ __forceinline__ v2f vfma(v2f a, v2f b, v2f c) {
    return __builtin_elementwise_fma(a, b, c);   // -> v_pk_fma_f32
}

// ---- cross-lane helpers (VALU pipe) ------------------------------------
template<int CTRL>
__device__ __forceinline__ float dppf(float v) {
    int r = __builtin_amdgcn_update_dpp(0, __float_as_int(v), CTRL, 0xF, 0xF, true);
    return __int_as_float(r);
}
template<int CTRL>
__device__ __forceinline__ v2f dpp2(v2f v) {
    v2f r;
    r.x = dppf<CTRL>(v.x);
    r.y = dppf<CTRL>(v.y);
    return r;
}

#if __has_builtin(__builtin_amdgcn_permlane32_swap)
#define HAVE_PL32 1
#else
#define HAVE_PL32 0
#endif
#if __has_builtin(__builtin_amdgcn_permlane16_swap)
#define HAVE_PL16 1
#else
#define HAVE_PL16 0
#endif

// (low-half bcast, high-half bcast) across lane-bit 5 for both components
__device__ __forceinline__ void split32v(v2f v, v2f& v0, v2f& v1) {
#if HAVE_PL32
    auto rx = __builtin_amdgcn_permlane32_swap(__float_as_uint(v.x), __float_as_uint(v.x), false, false);
    auto ry = __builtin_amdgcn_permlane32_swap(__float_as_uint(v.y), __float_as_uint(v.y), false, false);
    v0 = (v2f){__uint_as_float(rx[0]), __uint_as_float(ry[0])};
    v1 = (v2f){__uint_as_float(rx[1]), __uint_as_float(ry[1])};
#else
    v2f p;
    p.x = __shfl_xor(v.x, 32, 64);
    p.y = __shfl_xor(v.y, 32, 64);
    int bit = (__lane_id() >> 5) & 1;
    v0 = bit ? p : v;
    v1 = bit ? v : p;
#endif
}
// same across lane-bit 4
__device__ __forceinline__ void split16v(v2f v, v2f& v0, v2f& v1) {
#if HAVE_PL16
    auto rx = __builtin_amdgcn_permlane16_swap(__float_as_uint(v.x), __float_as_uint(v.x), false, false);
    auto ry = __builtin_amdgcn_permlane16_swap(__float_as_uint(v.y), __float_as_uint(v.y), false, false);
    v0 = (v2f){__uint_as_float(rx[0]), __uint_as_float(ry[0])};
    v1 = (v2f){__uint_as_float(rx[1]), __uint_as_float(ry[1])};
#else
    v2f p;
    p.x = __shfl_xor(v.x, 16, 64);
    p.y = __shfl_xor(v.y, 16, 64);
    int bit = (__lane_id() >> 4) & 1;
    v0 = bit ? p : v;
    v1 = bit ? v : p;
#endif
}
// scalar versions for the reduction
__device__ __forceinline__ void split16(float v, float& v0, float& v1) {
#if HAVE_PL16
    auto r = __builtin_amdgcn_permlane16_swap(__float_as_uint(v), __float_as_uint(v), false, false);
    v0 = __uint_as_float(r[0]);
    v1 = __uint_as_float(r[1]);
#else
    float p = __shfl_xor(v, 16, 64);
    int bit = (__lane_id() >> 4) & 1;
    v0 = bit ? p : v;
    v1 = bit ? v : p;
#endif
}
__device__ __forceinline__ void split32(float v, float& v0, float& v1) {
#if HAVE_PL32
    auto r = __builtin_amdgcn_permlane32_swap(__float_as_uint(v), __float_as_uint(v), false, false);
    v0 = __uint_as_float(r[0]);
    v1 = __uint_as_float(r[1]);
#else
    float p = __shfl_xor(v, 32, 64);
    int bit = (__lane_id() >> 5) & 1;
    v0 = bit ? p : v;
    v1 = bit ? v : p;
#endif
}

// ---- butterfly variants (state: a[e] = (re, im) packed) ----------------
template<int ST>
__device__ __forceinline__ void reg_wire(v2f a[16], float cy, float sy) {
    const v2f cc = splat(cy), ss = splat(sy);
    #pragma unroll
    for (int e0 = 0; e0 < 16; ++e0) {
        if ((e0 & ST) == 0) {
            const int e1 = e0 | ST;
            v2f A0 = a[e0], A1 = a[e1];
            a[e0] = vfma(cc, A0, -(ss * A1));
            a[e1] = vfma(ss, A0, cc * A1);
        }
    }
}

// masks 1,2,8 via single DPP partner
template<int CTRL>
__device__ __forceinline__ void dpp_wire(v2f a[16], float cy, float sy, int bit) {
    const v2f cc = splat(cy), sv = splat(bit ? sy : -sy);
    #pragma unroll
    for (int e = 0; e < 16; ++e) {
        v2f p = dpp2<CTRL>(a[e]);
        a[e] = vfma(sv, p, cc * a[e]);
    }
}

// mask 4: row_shr:4 sources lane i-4 (bit==1 lanes), row_shl:4 sources i+4 (bit==0)
__device__ __forceinline__ void xor4_wire(v2f a[16], float cy, float sy, int bit) {
    const v2f cc = splat(cy), sv = splat(bit ? sy : -sy);
    #pragma unroll
    for (int e = 0; e < 16; ++e) {
        v2f pS = dpp2<0x114>(a[e]);   // src lane i-4
        v2f pL = dpp2<0x104>(a[e]);   // src lane i+4
        v2f p = bit ? pS : pL;
        a[e] = vfma(sv, p, cc * a[e]);
    }
}

// masks 16/32 via permlane swap: n = ka*v0 + kb*v1
template<bool IS32>
__device__ __forceinline__ void pl_wire(v2f a[16], float cy, float sy, int bit) {
    const v2f ka = splat(bit ? sy : cy), kb = splat(bit ? cy : -sy);
    #pragma unroll
    for (int e = 0; e < 16; ++e) {
        v2f A0, A1;
        if constexpr (IS32) split32v(a[e], A0, A1);
        else                split16v(a[e], A0, A1);
        a[e] = vfma(ka, A0, kb * A1);
    }
}

// all-VALU wave sum
__device__ __forceinline__ float wave_sum(float y) {
    y += dppf<0xB1>(y);     // xor 1
    y += dppf<0x4E>(y);     // xor 2
    y += dppf<0x124>(y);    // row_ror:4
    y += dppf<0x128>(y);    // row_ror:8
    float a, b;
    split16(y, a, b); y = a + b;
    split32(y, a, b); y = a + b;
    return y;
}

__global__ __launch_bounds__(TPB) void qsim_kernel(
    const float* __restrict__ x,        // (512, 12)
    const float* __restrict__ params,   // (48, 12)
    const float* __restrict__ head_w,   // (2, 12)
    const float* __restrict__ head_b,   // (2,)
    float* __restrict__ out)            // (512, 2)
{
    __shared__ float4 exch[2][8][TPB];  // 64 KB double-buffered exchange
    __shared__ float  cys[DEPTH * NQ];
    __shared__ float  sys[DEPTH * NQ];
    __shared__ float  red[4][13];

    const int b = blockIdx.x;
    const int t = threadIdx.x;

    // gate angle tables (batch-independent)
    if (t < DEPTH * NQ) {
        int i = t % NQ;
        float sv, cv;
        __sincosf(0.5f * params[t * NQ + i], &sv, &cv);
        cys[t] = cv;
        sys[t] = sv;
    }

    // per-sample RX coefficients
    float c[NQ], s[NQ];
    #pragma unroll
    for (int i = 0; i < NQ; ++i)
        __sincosf(0.5f * x[b * NQ + i], &s[i], &c[i]);

    // state: amp index k = (t<<4)|e ; a[e] = (re, im)
    v2f a[16];
    {
        float P = 1.0f;
        #pragma unroll
        for (int j = 0; j < 8; ++j)
            P *= ((t >> (7 - j)) & 1) ? s[j] : c[j];
        const int pt = __popc(t);
        #pragma unroll
        for (int e = 0; e < 16; ++e) {
            float q = ((e >> 3) & 1 ? s[8]  : c[8])
                    * ((e >> 2) & 1 ? s[9]  : c[9])
                    * ((e >> 1) & 1 ? s[10] : c[10])
                    * ((e     ) & 1 ? s[11] : c[11]);
            float m = P * q;
            int p = (pt + __popc(e)) & 3;   // (-i)^popc(k)
            float re = (p == 0) ? m : ((p == 2) ? -m : 0.0f);
            float im = (p == 1) ? -m : ((p == 3) ? m : 0.0f);
            a[e] = (v2f){re, im};
        }
    }

    // CZ signs as +-1.0f per local amp (negate where popc(k & (k>>1)) odd)
    float czs[16];
    #pragma unroll
    for (int e = 0; e < 16; ++e) {
        int k = (t << 4) | e;
        czs[e] = __int_as_float(0x3f800000u | (unsigned)((__popc(k & (k >> 1)) & 1) << 31));
    }

    const int wa = (t >> 7) & 1;   // wire-0 bit
    const int wb = (t >> 6) & 1;   // wire-1 bit
    const int tb = t ^ 64, ta = t ^ 128, tab = t ^ 192;

    __syncthreads();   // tables ready

    #pragma unroll
    for (int d = 0; d < DEPTH; ++d) {
        const int base = d * NQ;

        // elem-bit wires 8..11
        reg_wire<8>(a, cys[base + 8],  sys[base + 8]);
        reg_wire<4>(a, cys[base + 9],  sys[base + 9]);
        reg_wire<2>(a, cys[base + 10], sys[base + 10]);
        reg_wire<1>(a, cys[base + 11], sys[base + 11]);

        // lane-bit wires 2..7 (all VALU pipe)
        pl_wire<true >(a, cys[base + 2], sys[base + 2], (t >> 5) & 1);
        pl_wire<false>(a, cys[base + 3], sys[base + 3], (t >> 4) & 1);
        dpp_wire<0x128>(a, cys[base + 4], sys[base + 4], (t >> 3) & 1); // xor 8
        xor4_wire      (a, cys[base + 5], sys[base + 5], (t >> 2) & 1); // xor 4
        dpp_wire<0x4E >(a, cys[base + 6], sys[base + 6], (t >> 1) & 1); // xor 2
        dpp_wire<0xB1 >(a, cys[base + 7], sys[base + 7], (t     ) & 1); // xor 1

        // wires 0,1 fused: 4-way exchange across thread bits 7,6 via LDS.
        // Double-buffered: one barrier per depth (write buf[d&1] -> barrier ->
        // read). Reads of buf[p] at depth d complete before depth d+1's
        // barrier, which precedes depth d+2's overwrite of buf[p].
        {
            const float c0 = cys[base + 0], s0 = sys[base + 0];
            const float c1 = cys[base + 1], s1 = sys[base + 1];
            const float sa = wa ? s0 : -s0;
            const float sb = wb ? s1 : -s1;
            const v2f koo = splat(c0 * c1);
            const v2f kb2 = splat(c0 * sb);   // partner t^64
            const v2f ka2 = splat(sa * c1);   // partner t^128
            const v2f kab = splat(sa * sb);   // partner t^192

            float4 (*buf)[TPB] = exch[d & 1];
            #pragma unroll
            for (int j = 0; j < 8; ++j)
                buf[j][t] = make_float4(a[2*j].x, a[2*j].y, a[2*j+1].x, a[2*j+1].y);
            __syncthreads();
            #pragma unroll
            for (int j = 0; j < 8; ++j) {
                float4 B  = buf[j][tb];
                float4 A  = buf[j][ta];
                float4 AB = buf[j][tab];
                v2f B0 = (v2f){B.x,  B.y},  B1 = (v2f){B.z,  B.w};
                v2f A0 = (v2f){A.x,  A.y},  A1 = (v2f){A.z,  A.w};
                v2f C0 = (v2f){AB.x, AB.y}, C1 = (v2f){AB.z, AB.w};
                a[2*j]   = vfma(koo, a[2*j],   vfma(kb2, B0, vfma(ka2, A0, kab * C0)));
                a[2*j+1] = vfma(koo, a[2*j+1], vfma(kb2, B1, vfma(ka2, A1, kab * C1)));
            }
        }

        // CZ signs (skip last depth: |amp|^2 unaffected)
        if (d < DEPTH - 1) {
            #pragma unroll
            for (int e = 0; e < 16; ++e)
                a[e] = a[e] * splat(czs[e]);
        }
    }

    // ---- reduction: T and per-wire S ----
    v2f t2 = splat(0.f), q0 = splat(0.f), q1 = splat(0.f), q2 = splat(0.f), q3 = splat(0.f);
    #pragma unroll
    for (int e = 0; e < 16; ++e) {
        v2f ae = a[e];
        t2 = vfma(ae, ae, t2);
        if (e & 8) q0 = vfma(ae, ae, q0);
        if (e & 4) q1 = vfma(ae, ae, q1);
        if (e & 2) q2 = vfma(ae, ae, q2);
        if (e & 1) q3 = vfma(ae, ae, q3);
    }
    float T = t2.x + t2.y;
    float v[13];
    v[0] = T;
    #pragma unroll
    for (int w = 0; w < 8; ++w)
        v[1 + w] = ((t >> (7 - w)) & 1) ? T : 0.0f;   // wires 0..7
    v[9]  = q0.x + q0.y;
    v[10] = q1.x + q1.y;
    v[11] = q2.x + q2.y;
    v[12] = q3.x + q3.y;

    #pragma unroll
    for (int i = 0; i < 13; ++i)
        v[i] = wave_sum(v[i]);

    if ((t & 63) == 0) {
        #pragma unroll
        for (int i = 0; i < 13; ++i) red[t >> 6][i] = v[i];
    }
    __syncthreads();

    if (t == 0) {
        float Tt = red[0][0] + red[1][0] + red[2][0] + red[3][0];
        float l0 = head_b[0], l1 = head_b[1];
        #pragma unroll
        for (int w = 0; w < NQ; ++w) {
            float Sw = red[0][1 + w] + red[1][1 + w] + red[2][1 + w] + red[3][1 + w];
            float z = Tt - 2.0f * Sw;
            l0 += z * head_w[w];
            l1 += z * head_w[NQ + w];
        }
        float m = fmaxf(l0, l1);
        float lse = m + __logf(__expf(l0 - m) + __expf(l1 - m));
        out[b * 2 + 0] = l0 - lse;
        out[b * 2 + 1] = l1 - lse;
    }
}

extern "C" void kernel_launch(void* const* d_in, const int* in_sizes, int n_in,
                              void* d_out, int out_size, void* d_ws, size_t ws_size,
                              hipStream_t stream) {
    const float* x      = (const float*)d_in[0];
    const float* params = (const float*)d_in[1];
    const float* head_w = (const float*)d_in[2];
    const float* head_b = (const float*)d_in[3];
    float* out = (float*)d_out;

    const int batch = in_sizes[0] / NQ;   // 512
    qsim_kernel<<<batch, TPB, 0, stream>>>(x, params, head_w, head_b, out);
}

// Round 6
// 21.695 us; speedup vs baseline: 2.8072x; 1.0149x over previous
//
#include <hip/hip_runtime.h>
#include <math.h>

#define NQ    12
#define TPB   256
#define DEPTH 4

typedef float v2f __attribute__((ext_vector_type(2)));

__device__ __forceinline__ v2f splat(float s) { return (v2f){s, s}; }
__device__ __forceinline__ v2f vfma(v2f a, v2f b, v2f c) {
    return __builtin_elementwise_fma(a, b, c);   // -> v_pk_fma_f32
}

// readlane broadcast of a float (literal lane index), pure VALU/SALU
#define RL(v, l) __uint_as_float(__builtin_amdgcn_readlane(__float_as_uint(v), (l)))

// ---- cross-lane helpers (VALU pipe) ------------------------------------
template<int CTRL>
__device__ __forceinline__ float dppf(float v) {
    int r = __builtin_amdgcn_update_dpp(0, __float_as_int(v), CTRL, 0xF, 0xF, true);
    return __int_as_float(r);
}
template<int CTRL>
__device__ __forceinline__ v2f dpp2(v2f v) {
    v2f r;
    r.x = dppf<CTRL>(v.x);
    r.y = dppf<CTRL>(v.y);
    return r;
}

#if __has_builtin(__builtin_amdgcn_permlane32_swap)
#define HAVE_PL32 1
#else
#define HAVE_PL32 0
#endif
#if __has_builtin(__builtin_amdgcn_permlane16_swap)
#define HAVE_PL16 1
#else
#define HAVE_PL16 0
#endif

__device__ __forceinline__ void split32v(v2f v, v2f& v0, v2f& v1) {
#if HAVE_PL32
    auto rx = __builtin_amdgcn_permlane32_swap(__float_as_uint(v.x), __float_as_uint(v.x), false, false);
    auto ry = __builtin_amdgcn_permlane32_swap(__float_as_uint(v.y), __float_as_uint(v.y), false, false);
    v0 = (v2f){__uint_as_float(rx[0]), __uint_as_float(ry[0])};
    v1 = (v2f){__uint_as_float(rx[1]), __uint_as_float(ry[1])};
#else
    v2f p;
    p.x = __shfl_xor(v.x, 32, 64);
    p.y = __shfl_xor(v.y, 32, 64);
    int bit = (__lane_id() >> 5) & 1;
    v0 = bit ? p : v;
    v1 = bit ? v : p;
#endif
}
__device__ __forceinline__ void split16v(v2f v, v2f& v0, v2f& v1) {
#if HAVE_PL16
    auto rx = __builtin_amdgcn_permlane16_swap(__float_as_uint(v.x), __float_as_uint(v.x), false, false);
    auto ry = __builtin_amdgcn_permlane16_swap(__float_as_uint(v.y), __float_as_uint(v.y), false, false);
    v0 = (v2f){__uint_as_float(rx[0]), __uint_as_float(ry[0])};
    v1 = (v2f){__uint_as_float(rx[1]), __uint_as_float(ry[1])};
#else
    v2f p;
    p.x = __shfl_xor(v.x, 16, 64);
    p.y = __shfl_xor(v.y, 16, 64);
    int bit = (__lane_id() >> 4) & 1;
    v0 = bit ? p : v;
    v1 = bit ? v : p;
#endif
}
__device__ __forceinline__ void split16(float v, float& v0, float& v1) {
#if HAVE_PL16
    auto r = __builtin_amdgcn_permlane16_swap(__float_as_uint(v), __float_as_uint(v), false, false);
    v0 = __uint_as_float(r[0]);
    v1 = __uint_as_float(r[1]);
#else
    float p = __shfl_xor(v, 16, 64);
    int bit = (__lane_id() >> 4) & 1;
    v0 = bit ? p : v;
    v1 = bit ? v : p;
#endif
}
__device__ __forceinline__ void split32(float v, float& v0, float& v1) {
#if HAVE_PL32
    auto r = __builtin_amdgcn_permlane32_swap(__float_as_uint(v), __float_as_uint(v), false, false);
    v0 = __uint_as_float(r[0]);
    v1 = __uint_as_float(r[1]);
#else
    float p = __shfl_xor(v, 32, 64);
    int bit = (__lane_id() >> 5) & 1;
    v0 = bit ? p : v;
    v1 = bit ? v : p;
#endif
}

// ---- butterfly variants (state: a[e] = (re, im) packed) ----------------
template<int ST>
__device__ __forceinline__ void reg_wire(v2f a[16], float cy, float sy) {
    const v2f cc = splat(cy), ss = splat(sy);
    #pragma unroll
    for (int e0 = 0; e0 < 16; ++e0) {
        if ((e0 & ST) == 0) {
            const int e1 = e0 | ST;
            v2f A0 = a[e0], A1 = a[e1];
            a[e0] = vfma(cc, A0, -(ss * A1));
            a[e1] = vfma(ss, A0, cc * A1);
        }
    }
}

template<int CTRL>
__device__ __forceinline__ void dpp_wire(v2f a[16], float cy, float sy, int bit) {
    const v2f cc = splat(cy), sv = splat(bit ? sy : -sy);
    #pragma unroll
    for (int e = 0; e < 16; ++e) {
        v2f p = dpp2<CTRL>(a[e]);
        a[e] = vfma(sv, p, cc * a[e]);
    }
}

// mask 4: row_shr:4 sources lane i-4 (bit==1), row_shl:4 sources i+4 (bit==0)
__device__ __forceinline__ void xor4_wire(v2f a[16], float cy, float sy, int bit) {
    const v2f cc = splat(cy), sv = splat(bit ? sy : -sy);
    #pragma unroll
    for (int e = 0; e < 16; ++e) {
        v2f pS = dpp2<0x114>(a[e]);
        v2f pL = dpp2<0x104>(a[e]);
        v2f p = bit ? pS : pL;
        a[e] = vfma(sv, p, cc * a[e]);
    }
}

template<bool IS32>
__device__ __forceinline__ void pl_wire(v2f a[16], float cy, float sy, int bit) {
    const v2f ka = splat(bit ? sy : cy), kb = splat(bit ? cy : -sy);
    #pragma unroll
    for (int e = 0; e < 16; ++e) {
        v2f A0, A1;
        if constexpr (IS32) split32v(a[e], A0, A1);
        else                split16v(a[e], A0, A1);
        a[e] = vfma(ka, A0, kb * A1);
    }
}

__device__ __forceinline__ float wave_sum(float y) {
    y += dppf<0xB1>(y);
    y += dppf<0x4E>(y);
    y += dppf<0x124>(y);    // row_ror:4
    y += dppf<0x128>(y);    // row_ror:8
    float a, b;
    split16(y, a, b); y = a + b;
    split32(y, a, b); y = a + b;
    return y;
}

__global__ __launch_bounds__(TPB) void qsim_kernel(
    const float* __restrict__ x,        // (512, 12)
    const float* __restrict__ params,   // (48, 12)
    const float* __restrict__ head_w,   // (2, 12)
    const float* __restrict__ head_b,   // (2,)
    float* __restrict__ out)            // (512, 2)
{
    __shared__ float4 exch[2][8][TPB];  // 64 KB double-buffered exchange
    __shared__ float  red[4][13];

    const int b = blockIdx.x;
    const int t = threadIdx.x;
    const int l = t & 63;

    // One sincos per thread, lane-parallel:
    //   lanes 0..47  -> RY angle (d,i) = l/12, l%12: 0.5*params[l*12 + l%12]
    //   lanes 48..59 -> RX angle 0.5*x[b*12 + (l-48)]
    float cv, sv;
    {
        int li   = l % 12;
        int idx1 = (l < 48) ? (l * 12 + li) : 0;
        float v1 = params[idx1];
        int i2   = l - 48;
        int idx2 = (i2 >= 0 && i2 < 12) ? (b * 12 + i2) : 0;
        float v2 = x[idx2];
        float th = 0.5f * ((l < 48) ? v1 : ((i2 >= 0 && i2 < 12) ? v2 : 0.0f));
        __sincosf(th, &sv, &cv);
    }
    // coefficient broadcast: RY (d,w) -> lane d*12+w ; RX i -> lane 48+i
    #define CY(d, w) RL(cv, (d) * 12 + (w))
    #define SY(d, w) RL(sv, (d) * 12 + (w))

    // state: amp index k = (t<<4)|e ; a[e] = (re, im)
    v2f a[16];
    {
        float cx[12], sx[12];
        #pragma unroll
        for (int i = 0; i < 12; ++i) {
            cx[i] = RL(cv, 48 + i);
            sx[i] = RL(sv, 48 + i);
        }
        float P = 1.0f;
        #pragma unroll
        for (int j = 0; j < 8; ++j)
            P *= ((t >> (7 - j)) & 1) ? sx[j] : cx[j];
        // q products over wires 8..11 (e bits 3..0)
        float qh[4], ql[4];
        qh[0] = cx[8] * cx[9];  qh[1] = cx[8] * sx[9];
        qh[2] = sx[8] * cx[9];  qh[3] = sx[8] * sx[9];
        ql[0] = cx[10] * cx[11]; ql[1] = cx[10] * sx[11];
        ql[2] = sx[10] * cx[11]; ql[3] = sx[10] * sx[11];
        // phase (-i)^popc(k): base u = (-i)^popc(t), rotated by popc(e)
        int p = __popc(t) & 3;
        float ur = (p == 0) ? 1.f : ((p == 2) ? -1.f : 0.f);
        float ui = (p == 1) ? -1.f : ((p == 3) ? 1.f : 0.f);
        v2f u[4] = { (v2f){ur, ui}, (v2f){ui, -ur}, (v2f){-ur, -ui}, (v2f){-ui, ur} };
        #pragma unroll
        for (int e = 0; e < 16; ++e) {
            float m = P * qh[e >> 2] * ql[e & 3];
            a[e] = splat(m) * u[__popc(e) & 3];
        }
    }

    // CZ signs as +-1.0f per local amp (negate where popc(k & (k>>1)) odd)
    float czs[16];
    #pragma unroll
    for (int e = 0; e < 16; ++e) {
        int k = (t << 4) | e;
        czs[e] = __int_as_float(0x3f800000u | (unsigned)((__popc(k & (k >> 1)) & 1) << 31));
    }

    const int wa = (t >> 7) & 1;   // wire-0 bit
    const int wb = (t >> 6) & 1;   // wire-1 bit
    const int tb = t ^ 64, ta = t ^ 128, tab = t ^ 192;

    #pragma unroll
    for (int d = 0; d < DEPTH; ++d) {
        // elem-bit wires 8..11
        reg_wire<8>(a, CY(d, 8),  SY(d, 8));
        reg_wire<4>(a, CY(d, 9),  SY(d, 9));
        reg_wire<2>(a, CY(d, 10), SY(d, 10));
        reg_wire<1>(a, CY(d, 11), SY(d, 11));

        // lane-bit wires 2..7 (all VALU pipe)
        pl_wire<true >(a, CY(d, 2), SY(d, 2), (t >> 5) & 1);
        pl_wire<false>(a, CY(d, 3), SY(d, 3), (t >> 4) & 1);
        dpp_wire<0x128>(a, CY(d, 4), SY(d, 4), (t >> 3) & 1); // xor 8
        xor4_wire      (a, CY(d, 5), SY(d, 5), (t >> 2) & 1); // xor 4
        dpp_wire<0x4E >(a, CY(d, 6), SY(d, 6), (t >> 1) & 1); // xor 2
        dpp_wire<0xB1 >(a, CY(d, 7), SY(d, 7), (t     ) & 1); // xor 1

        // wires 0,1 fused: 4-way exchange across thread bits 7,6 via LDS.
        // Double-buffered, one barrier per depth (see R5 hazard analysis).
        {
            const float c0 = CY(d, 0), s0 = SY(d, 0);
            const float c1 = CY(d, 1), s1 = SY(d, 1);
            const float sa = wa ? s0 : -s0;
            const float sb = wb ? s1 : -s1;
            const v2f koo = splat(c0 * c1);
            const v2f kb2 = splat(c0 * sb);   // partner t^64
            const v2f ka2 = splat(sa * c1);   // partner t^128
            const v2f kab = splat(sa * sb);   // partner t^192

            float4 (*buf)[TPB] = exch[d & 1];
            #pragma unroll
            for (int j = 0; j < 8; ++j)
                buf[j][t] = make_float4(a[2*j].x, a[2*j].y, a[2*j+1].x, a[2*j+1].y);
            __syncthreads();
            #pragma unroll
            for (int j = 0; j < 8; ++j) {
                float4 B  = buf[j][tb];
                float4 A  = buf[j][ta];
                float4 AB = buf[j][tab];
                v2f B0 = (v2f){B.x,  B.y},  B1 = (v2f){B.z,  B.w};
                v2f A0 = (v2f){A.x,  A.y},  A1 = (v2f){A.z,  A.w};
                v2f C0 = (v2f){AB.x, AB.y}, C1 = (v2f){AB.z, AB.w};
                a[2*j]   = vfma(koo, a[2*j],   vfma(kb2, B0, vfma(ka2, A0, kab * C0)));
                a[2*j+1] = vfma(koo, a[2*j+1], vfma(kb2, B1, vfma(ka2, A1, kab * C1)));
            }
        }

        // CZ signs (skip last depth: |amp|^2 unaffected)
        if (d < DEPTH - 1) {
            #pragma unroll
            for (int e = 0; e < 16; ++e)
                a[e] = a[e] * splat(czs[e]);
        }
    }

    // ---- reduction: T and per-wire S ----
    v2f t2 = splat(0.f), q0 = splat(0.f), q1 = splat(0.f), q2 = splat(0.f), q3 = splat(0.f);
    #pragma unroll
    for (int e = 0; e < 16; ++e) {
        v2f ae = a[e];
        t2 = vfma(ae, ae, t2);
        if (e & 8) q0 = vfma(ae, ae, q0);
        if (e & 4) q1 = vfma(ae, ae, q1);
        if (e & 2) q2 = vfma(ae, ae, q2);
        if (e & 1) q3 = vfma(ae, ae, q3);
    }
    float T = t2.x + t2.y;
    float v[13];
    v[0] = T;
    #pragma unroll
    for (int w = 0; w < 8; ++w)
        v[1 + w] = ((t >> (7 - w)) & 1) ? T : 0.0f;   // wires 0..7
    v[9]  = q0.x + q0.y;
    v[10] = q1.x + q1.y;
    v[11] = q2.x + q2.y;
    v[12] = q3.x + q3.y;

    #pragma unroll
    for (int i = 0; i < 13; ++i)
        v[i] = wave_sum(v[i]);

    if ((t & 63) == 0) {
        #pragma unroll
        for (int i = 0; i < 13; ++i) red[t >> 6][i] = v[i];
    }
    __syncthreads();

    if (t == 0) {
        float Tt = red[0][0] + red[1][0] + red[2][0] + red[3][0];
        float l0 = head_b[0], l1 = head_b[1];
        #pragma unroll
        for (int w = 0; w < NQ; ++w) {
            float Sw = red[0][1 + w] + red[1][1 + w] + red[2][1 + w] + red[3][1 + w];
            float z = Tt - 2.0f * Sw;
            l0 += z * head_w[w];
            l1 += z * head_w[NQ + w];
        }
        float m = fmaxf(l0, l1);
        float lse = m + __logf(__expf(l0 - m) + __expf(l1 - m));
        out[b * 2 + 0] = l0 - lse;
        out[b * 2 + 1] = l1 - lse;
    }
}

extern "C" void kernel_launch(void* const* d_in, const int* in_sizes, int n_in,
                              void* d_out, int out_size, void* d_ws, size_t ws_size,
                              hipStream_t stream) {
    const float* x      = (const float*)d_in[0];
    const float* params = (const float*)d_in[1];
    const float* head_w = (const float*)d_in[2];
    const float* head_b = (const float*)d_in[3];
    float* out = (float*)d_out;

    const int batch = in_sizes[0] / NQ;   // 512
    qsim_kernel<<<batch, TPB, 0, stream>>>(x, params, head_w, head_b, out);
}